// Round 8
// baseline (1425.943 us; speedup 1.0000x reference)
//
#include <hip/hip_runtime.h>

// DubinsLSTM R8: weights pinned in AGPRs (unified gfx950 reg file).
// R5-R7 signature: VGPR_Count=128 + ~6.9MB scratch stores -> RA spilled the
// asm-"+v"-pinned weight frags because arch-VGPR demand (~236) exceeded its
// chosen 128 budget, while the AGPR half of the unified file sat idle.
// R8 pins the 43 resident fragments with asm "+a" (AGPR class). MFMA reads
// B-operands from AGPR directly (ISA sec.10: A,B from VGPR or AGPR; AV-class
// intrinsic operands) -> zero copies, zero scratch. Arch-VGPR demand ~85.

#define BB 1024
#define TT 200
#define INDIM 3
#define CDIM 4
#define HH 128
#define OD 3
#define GG 512
#define EPB 16
#define LDA 264              // halves; 528B row stride
#define W1F_OFF 65536        // halves
#define WF_TOTAL 196608      // halves (384 KB)

// smem blob (bytes):
#define A1_OFF    8448       // A0 [16][264] f16
#define WLDS_OFF  16896      // 5 frags x 8 waves x 64 lanes x 16B = 40960
#define B1T_OFF   57856      // b1t [8][4][16] f32 = 2048
#define WOT_OFF   59904      // WoT [3][128] f32 = 1536
#define PREVS_OFF 61440      // prevs [16][4] f32 = 256
#define SMEM_SZ   61696

typedef _Float16 f16x8 __attribute__((ext_vector_type(8)));
typedef _Float16 f16x4 __attribute__((ext_vector_type(4)));
typedef float f32x4 __attribute__((ext_vector_type(4)));

__device__ __forceinline__ float sigf(float x) {
    return __fdividef(1.f, 1.f + __expf(-x));
}
__device__ __forceinline__ float tanhfast(float x) {
    return 1.f - __fdividef(2.f, __expf(2.f * x) + 1.f);
}
// pin a 16B fragment into AGPRs (unified file; MFMA reads A/B from AGPR)
__device__ __forceinline__ void pinA(uint4& v) {
    asm volatile("" : "+a"(v.x), "+a"(v.y), "+a"(v.z), "+a"(v.w));
}

// Repack Whh0 / [Wih1;Whh1] into MFMA-B fragment-linear f16 (layout verified
// R4/R5): frag(nt,ks): lane l holds B[k=ks*32+8*(l>>4)+j][col=nt*16+(l&15)].
__global__ void repack_frag_kernel(const float* __restrict__ Whh0,
                                   const float* __restrict__ Wih1,
                                   const float* __restrict__ Whh1,
                                   _Float16* __restrict__ wf) {
    int idx = blockIdx.x * 256 + threadIdx.x;
    if (idx < 65536) {
        int nt = idx >> 11;
        int ks = (idx >> 9) & 3;
        int l  = (idx >> 3) & 63;
        int j  = idx & 7;
        int k  = ks * 32 + ((l >> 4) << 3) + j;
        int col = nt * 16 + (l & 15);
        wf[idx] = (_Float16)Whh0[k * GG + col];
    } else {
        int i2 = idx - 65536;
        int nt = i2 >> 12;
        int ks = (i2 >> 9) & 7;
        int l  = (i2 >> 3) & 63;
        int j  = i2 & 7;
        int k  = ks * 32 + ((l >> 4) << 3) + j;
        int col = nt * 16 + (l & 15);
        float v = (k < HH) ? Wih1[k * GG + col] : Whh1[(k - HH) * GG + col];
        wf[idx] = (_Float16)v;
    }
}

__global__ __attribute__((amdgpu_waves_per_eu(2, 2)))
__launch_bounds__(512) void dubins_lstm_mfma_kernel(
    const float* __restrict__ conds,
    const float* __restrict__ target_seq,
    const int*   __restrict__ lengths,
    const float* __restrict__ tf_rand,
    const float* __restrict__ Wc,
    const float* __restrict__ bc,
    const float* __restrict__ Wih0,
    const float* __restrict__ b0,
    const float* __restrict__ b1,
    const float* __restrict__ Wo,
    const float* __restrict__ bo,
    const _Float16* __restrict__ wf,
    float* __restrict__ out)
{
    __shared__ __align__(16) unsigned char smem[SMEM_SZ];
    _Float16* A0    = (_Float16*)smem;
    _Float16* A1    = (_Float16*)(smem + A1_OFF);
    uint4*    wldsU = (uint4*)(smem + WLDS_OFF);
    float*    cembL = (float*)(smem + WLDS_OFF);    // alias: pre-loop only
    float*    b1t   = (float*)(smem + B1T_OFF);     // [w][q][u]
    float*    WoT   = (float*)(smem + WOT_OFF);     // [d][k]
    float*    prevs = (float*)(smem + PREVS_OFF);   // [m][4]

    const int tid  = threadIdx.x;
    const int w    = tid >> 6;
    const int l    = tid & 63;
    const int lo16 = l & 15;
    const int lhi  = l >> 4;
    const int b_base = blockIdx.x * EPB;
    const int om = tid >> 5;       // P4 element
    const int pl = tid & 31;       // P4 lane

    // ---- zero A0+A1, prevs; fill b1t, WoT ----
    for (int i = tid; i < 4224; i += 512) ((unsigned int*)smem)[i] = 0u;
    if (tid < 64) prevs[tid] = 0.f;
    {   // b1t[w][q][u] = b1[(w+8q)*16+u]
        int fw = tid >> 6, fq = (tid >> 4) & 3, fu = tid & 15;
        b1t[tid] = b1[(fw + 8 * fq) * 16 + fu];
    }
    if (tid < 384) WoT[(tid % 3) * 128 + tid / 3] = Wo[tid];

    // ---- cemb[m][k] (f32, aliased LDS) ----
    {
        int m  = tid >> 5;
        int k0 = (tid & 31) * 4;
        float cd[CDIM];
        #pragma unroll
        for (int d = 0; d < CDIM; ++d) cd[d] = conds[(b_base + m) * CDIM + d];
        #pragma unroll
        for (int kk = 0; kk < 4; ++kk) {
            int k = k0 + kk;
            float v = bc[k];
            #pragma unroll
            for (int d = 0; d < CDIM; ++d) v = fmaf(cd[d], Wc[d * HH + k], v);
            cembL[m * HH + k] = v;
        }
    }
    __syncthreads();

    // ---- cz (time-invariant C-init) -> per-thread packed f16 regs ----
    f16x4 czp[4];
    {
        f32x4 cz[4];
        int colq[4];
        #pragma unroll
        for (int q = 0; q < 4; ++q) {
            colq[q] = (w + 8 * q) * 16 + lo16;
            float bz = b0[colq[q]];
            cz[q] = {bz, bz, bz, bz};
        }
        for (int k = 0; k < HH; ++k) {
            float cv0 = cembL[(lhi * 4 + 0) * HH + k];
            float cv1 = cembL[(lhi * 4 + 1) * HH + k];
            float cv2 = cembL[(lhi * 4 + 2) * HH + k];
            float cv3 = cembL[(lhi * 4 + 3) * HH + k];
            #pragma unroll
            for (int q = 0; q < 4; ++q) {
                float wv = Wih0[(INDIM + k) * GG + colq[q]];
                cz[q][0] = fmaf(cv0, wv, cz[q][0]);
                cz[q][1] = fmaf(cv1, wv, cz[q][1]);
                cz[q][2] = fmaf(cv2, wv, cz[q][2]);
                cz[q][3] = fmaf(cv3, wv, cz[q][3]);
            }
        }
        #pragma unroll
        for (int q = 0; q < 4; ++q)
            #pragma unroll
            for (int r = 0; r < 4; ++r) czp[q][r] = (_Float16)cz[q][r];
        __syncthreads();   // cembL reads done; wlds region may be overwritten
    }

    // ---- wprev (12 loop-invariant regs) ----
    float wprev[4][3];
    #pragma unroll
    for (int q = 0; q < 4; ++q)
        #pragma unroll
        for (int d = 0; d < 3; ++d) wprev[q][d] = Wih0[d * GG + (w + 8 * q) * 16 + lo16];
    const float bov  = (pl < OD) ? bo[pl] : 0.f;
    const int   plen = lengths[b_base + om];

    // ---- weight fragments -> AGPRs (pinned) + 5 frags -> LDS ----
    const uint4* __restrict__ w0g = reinterpret_cast<const uint4*>(wf) + (w * 256 + l);
    const uint4* __restrict__ w1g = reinterpret_cast<const uint4*>(wf + W1F_OFF) + (w * 512 + l);
    uint4 w0r[16];
    uint4 w1r[27];
    #pragma unroll
    for (int f = 0; f < 16; ++f) {
        int ks = f >> 2, q = f & 3;
        w0r[f] = w0g[q * 2048 + ks * 64];
        pinA(w0r[f]);
    }
    #pragma unroll
    for (int f = 0; f < 27; ++f) {
        int ks = f >> 2, q = f & 3;
        w1r[f] = w1g[q * 4096 + ks * 64];
        pinA(w1r[f]);
    }
    #pragma unroll
    for (int fi = 0; fi < 5; ++fi) {
        int f = 27 + fi, ks = f >> 2, q = f & 3;
        wldsU[(w * 5 + fi) * 64 + l] = w1g[q * 4096 + ks * 64];
    }
    __syncthreads();

    float c0s[4] = {0.f, 0.f, 0.f, 0.f};
    float c1s[4] = {0.f, 0.f, 0.f, 0.f};

    for (int t = 0; t < TT; ++t) {
        _Float16* Ac = (t & 1) ? A1 : A0;
        _Float16* An = (t & 1) ? A0 : A1;
        const f16x8* apC = reinterpret_cast<const f16x8*>(Ac + lo16 * LDA);
        const f16x8* apN = reinterpret_cast<const f16x8*>(An + lo16 * LDA);

        // prefetch per-step inputs
        const float tfv = tf_rand[t * BB + b_base + om];
        float tgtv = 0.f;
        if (pl < OD) tgtv = target_seq[((b_base + om) * TT + t) * OD + pl];

        f32x4 acc[4];

        // ---- P0: z0 = cz + prev@Wp + h0old@Whh0 ----
        #pragma unroll
        for (int q = 0; q < 4; ++q)
            acc[q] = {(float)czp[q][0], (float)czp[q][1],
                      (float)czp[q][2], (float)czp[q][3]};
        #pragma unroll
        for (int r = 0; r < 4; ++r) {
            const float4 pv = *reinterpret_cast<const float4*>(prevs + (lhi * 4 + r) * 4);
            #pragma unroll
            for (int q = 0; q < 4; ++q)
                acc[q][r] = fmaf(pv.z, wprev[q][2],
                            fmaf(pv.y, wprev[q][1],
                            fmaf(pv.x, wprev[q][0], acc[q][r])));
        }
        #pragma unroll
        for (int ks = 0; ks < 4; ++ks) {
            const f16x8 a = apC[ks * 4 + lhi];
            #pragma unroll
            for (int q = 0; q < 4; ++q)
                acc[q] = __builtin_amdgcn_mfma_f32_16x16x32_f16(
                             a, __builtin_bit_cast(f16x8, w0r[ks * 4 + q]), acc[q], 0, 0, 0);
        }

        // ---- P1: gate-0 (lane-local), write h0new -> An ----
        #pragma unroll
        for (int r = 0; r < 4; ++r) {
            const float zi = acc[0][r], zf = acc[1][r], zg = acc[2][r], zo = acc[3][r];
            c0s[r] = sigf(zf) * c0s[r] + sigf(zi) * tanhfast(zg);
            An[(lhi * 4 + r) * LDA + w * 16 + lo16] = (_Float16)(sigf(zo) * tanhfast(c0s[r]));
        }
        __syncthreads();   // bar_a: h0new visible

        // ---- P2: z1 = b1 + [h0new ; h1old] @ W1 ----
        #pragma unroll
        for (int q = 0; q < 4; ++q) {
            const float bv = b1t[(w * 4 + q) * 16 + lo16];
            acc[q] = {bv, bv, bv, bv};
        }
        #pragma unroll
        for (int ks = 0; ks < 8; ++ks) {
            const f16x8 a = (ks < 4) ? apN[ks * 4 + lhi]
                                     : apC[16 + (ks - 4) * 4 + lhi];
            #pragma unroll
            for (int q = 0; q < 4; ++q) {
                const int f = ks * 4 + q;
                f16x8 b;
                if (f < 27) b = __builtin_bit_cast(f16x8, w1r[f]);
                else        b = __builtin_bit_cast(f16x8, wldsU[(w * 5 + (f - 27)) * 64 + l]);
                acc[q] = __builtin_amdgcn_mfma_f32_16x16x32_f16(a, b, acc[q], 0, 0, 0);
            }
        }

        // ---- P3: gate-1 (lane-local), write h1new -> An ----
        #pragma unroll
        for (int r = 0; r < 4; ++r) {
            const float zi = acc[0][r], zf = acc[1][r], zg = acc[2][r], zo = acc[3][r];
            c1s[r] = sigf(zf) * c1s[r] + sigf(zi) * tanhfast(zg);
            An[(lhi * 4 + r) * LDA + HH + w * 16 + lo16] = (_Float16)(sigf(zo) * tanhfast(c1s[r]));
        }
        __syncthreads();   // bar_b: h1new visible

        // ---- P4: output projection + teacher forcing ----
        {
            const f16x4 hv = *reinterpret_cast<const f16x4*>(An + om * LDA + HH + pl * 4);
            const float h0_ = (float)hv[0], h1_ = (float)hv[1],
                        h2_ = (float)hv[2], h3_ = (float)hv[3];
            const float4 wv0 = *reinterpret_cast<const float4*>(WoT + 0 * 128 + pl * 4);
            const float4 wv1 = *reinterpret_cast<const float4*>(WoT + 1 * 128 + pl * 4);
            const float4 wv2 = *reinterpret_cast<const float4*>(WoT + 2 * 128 + pl * 4);
            float s0 = fmaf(h3_, wv0.w, fmaf(h2_, wv0.z, fmaf(h1_, wv0.y, h0_ * wv0.x)));
            float s1 = fmaf(h3_, wv1.w, fmaf(h2_, wv1.z, fmaf(h1_, wv1.y, h0_ * wv1.x)));
            float s2 = fmaf(h3_, wv2.w, fmaf(h2_, wv2.z, fmaf(h1_, wv2.y, h0_ * wv2.x)));
            #pragma unroll
            for (int sh = 16; sh >= 1; sh >>= 1) {
                s0 += __shfl_xor(s0, sh, 32);
                s1 += __shfl_xor(s1, sh, 32);
                s2 += __shfl_xor(s2, sh, 32);
            }
            if (pl < OD) {
                const float sv = (pl == 0) ? s0 : (pl == 1) ? s1 : s2;
                const float pred = sv + bov;
                const int bg = b_base + om;
                out[(bg * TT + t) * OD + pl] = pred;
                const bool use_tf = (tfv < 0.5f) && (t < plen);
                prevs[om * 4 + pl] = use_tf ? tgtv : pred;
            }
        }
        __syncthreads();   // bar_c: prevs ready for next step
    }
}

extern "C" void kernel_launch(void* const* d_in, const int* in_sizes, int n_in,
                              void* d_out, int out_size, void* d_ws, size_t ws_size,
                              hipStream_t stream) {
    const float* conds   = (const float*)d_in[0];
    const float* target  = (const float*)d_in[1];
    const int*   lengths = (const int*)d_in[2];
    const float* tfr     = (const float*)d_in[3];
    const float* Wc      = (const float*)d_in[4];
    const float* bc      = (const float*)d_in[5];
    const float* Wih0    = (const float*)d_in[6];
    const float* Whh0    = (const float*)d_in[7];
    const float* b0      = (const float*)d_in[8];
    const float* Wih1    = (const float*)d_in[9];
    const float* Whh1    = (const float*)d_in[10];
    const float* b1      = (const float*)d_in[11];
    const float* Wo      = (const float*)d_in[12];
    const float* bo      = (const float*)d_in[13];
    float* out = (float*)d_out;
    _Float16* wf = (_Float16*)d_ws;

    repack_frag_kernel<<<WF_TOTAL / 256, 256, 0, stream>>>(Whh0, Wih1, Whh1, wf);
    dubins_lstm_mfma_kernel<<<BB / EPB, 512, 0, stream>>>(
        conds, target, lengths, tfr, Wc, bc,
        Wih0, b0, b1, Wo, bo, wf, out);
}

// Round 9
// 1316.529 us; speedup vs baseline: 1.0831x; 1.0831x over previous
//
#include <hip/hip_runtime.h>

// DubinsLSTM R9: fit the RA's observed 128 arch / 128 accum split EXACTLY.
// R5-R8 all violated one class budget (~172 AGPR or ~240 arch) -> spill to
// scratch + per-step L2 reloads (signature: VGPR_Count=128, WRITE_SIZE~10MB).
// R9: 32 frags resident in AGPR (=128 exactly: L0 all 16 + L1 ks0..3);
// L1 ks4..7 streamed from L2 each step in 2 batches of 8 (32 arch regs each,
// short-lived; issue points chosen so L2 latency hides under compute; an
// opaque asm offset per iteration blocks LICM re-hoist+spill).
// czp -> per-TID LDS table (stride-16B b128, conflict-free; NOT wave-shared).

#define BB 1024
#define TT 200
#define INDIM 3
#define CDIM 4
#define HH 128
#define OD 3
#define GG 512
#define EPB 16
#define LDA 264              // halves; 528B row stride
#define W1F_OFF 65536        // halves
#define WF_TOTAL 196608      // halves (384 KB)

// smem blob (bytes):
#define A1_OFF    8448       // A0 [16][264] f16
#define CZL_OFF   16896      // czL: 2 planes x 512 tid x 16B = 16384 (alias cemb pre-loop)
#define B1T_OFF   33280      // b1t [8][4][16] f32 = 2048
#define WOT_OFF   35328      // WoT [3][128] f32 = 1536
#define PREVS_OFF 36864      // prevs [16][4] f32 = 256
#define SMEM_SZ   37120

typedef _Float16 f16x8 __attribute__((ext_vector_type(8)));
typedef _Float16 f16x4 __attribute__((ext_vector_type(4)));
typedef float f32x4 __attribute__((ext_vector_type(4)));

__device__ __forceinline__ float sigf(float x) {
    return __fdividef(1.f, 1.f + __expf(-x));
}
__device__ __forceinline__ float tanhfast(float x) {
    return 1.f - __fdividef(2.f, __expf(2.f * x) + 1.f);
}
// pin a 16B fragment into AGPRs (unified file; MFMA reads A/B from AGPR)
__device__ __forceinline__ void pinA(uint4& v) {
    asm volatile("" : "+a"(v.x), "+a"(v.y), "+a"(v.z), "+a"(v.w));
}

// Repack Whh0 / [Wih1;Whh1] into MFMA-B fragment-linear f16 (layout verified
// R4+): frag(nt,ks): lane l holds B[k=ks*32+8*(l>>4)+j][col=nt*16+(l&15)].
__global__ void repack_frag_kernel(const float* __restrict__ Whh0,
                                   const float* __restrict__ Wih1,
                                   const float* __restrict__ Whh1,
                                   _Float16* __restrict__ wf) {
    int idx = blockIdx.x * 256 + threadIdx.x;
    if (idx < 65536) {
        int nt = idx >> 11;
        int ks = (idx >> 9) & 3;
        int l  = (idx >> 3) & 63;
        int j  = idx & 7;
        int k  = ks * 32 + ((l >> 4) << 3) + j;
        int col = nt * 16 + (l & 15);
        wf[idx] = (_Float16)Whh0[k * GG + col];
    } else {
        int i2 = idx - 65536;
        int nt = i2 >> 12;
        int ks = (i2 >> 9) & 7;
        int l  = (i2 >> 3) & 63;
        int j  = i2 & 7;
        int k  = ks * 32 + ((l >> 4) << 3) + j;
        int col = nt * 16 + (l & 15);
        float v = (k < HH) ? Wih1[k * GG + col] : Whh1[(k - HH) * GG + col];
        wf[idx] = (_Float16)v;
    }
}

__global__ __attribute__((amdgpu_waves_per_eu(2, 2)))
__launch_bounds__(512) void dubins_lstm_mfma_kernel(
    const float* __restrict__ conds,
    const float* __restrict__ target_seq,
    const int*   __restrict__ lengths,
    const float* __restrict__ tf_rand,
    const float* __restrict__ Wc,
    const float* __restrict__ bc,
    const float* __restrict__ Wih0,
    const float* __restrict__ b0,
    const float* __restrict__ b1,
    const float* __restrict__ Wo,
    const float* __restrict__ bo,
    const _Float16* __restrict__ wf,
    float* __restrict__ out)
{
    __shared__ __align__(16) unsigned char smem[SMEM_SZ];
    _Float16* A0    = (_Float16*)smem;
    _Float16* A1    = (_Float16*)(smem + A1_OFF);
    _Float16* czLh  = (_Float16*)(smem + CZL_OFF);  // per-tid, stride 8 halves/plane
    float*    cembL = (float*)(smem + CZL_OFF);     // alias: pre-loop only
    float*    b1t   = (float*)(smem + B1T_OFF);     // [w][q][u]
    float*    WoT   = (float*)(smem + WOT_OFF);     // [d][k]
    float*    prevs = (float*)(smem + PREVS_OFF);   // [m][4]

    const int tid  = threadIdx.x;
    const int w    = tid >> 6;
    const int l    = tid & 63;
    const int lo16 = l & 15;
    const int lhi  = l >> 4;
    const int b_base = blockIdx.x * EPB;
    const int om = tid >> 5;       // P4 element
    const int pl = tid & 31;       // P4 lane

    // ---- zero A0+A1, prevs; fill b1t, WoT ----
    for (int i = tid; i < 4224; i += 512) ((unsigned int*)smem)[i] = 0u;
    if (tid < 64) prevs[tid] = 0.f;
    {   // b1t[w][q][u] = b1[(w+8q)*16+u]
        int fw = tid >> 6, fq = (tid >> 4) & 3, fu = tid & 15;
        b1t[tid] = b1[(fw + 8 * fq) * 16 + fu];
    }
    if (tid < 384) WoT[(tid % 3) * 128 + tid / 3] = Wo[tid];

    // ---- cemb[m][k] (f32, aliased LDS) ----
    {
        int m  = tid >> 5;
        int k0 = (tid & 31) * 4;
        float cd[CDIM];
        #pragma unroll
        for (int d = 0; d < CDIM; ++d) cd[d] = conds[(b_base + m) * CDIM + d];
        #pragma unroll
        for (int kk = 0; kk < 4; ++kk) {
            int k = k0 + kk;
            float v = bc[k];
            #pragma unroll
            for (int d = 0; d < CDIM; ++d) v = fmaf(cd[d], Wc[d * HH + k], v);
            cembL[m * HH + k] = v;
        }
    }
    __syncthreads();

    // ---- cz (time-invariant C-init) -> per-TID LDS table (f16) ----
    {
        f32x4 cz[4];
        int colq[4];
        #pragma unroll
        for (int q = 0; q < 4; ++q) {
            colq[q] = (w + 8 * q) * 16 + lo16;
            float bz = b0[colq[q]];
            cz[q] = {bz, bz, bz, bz};
        }
        for (int k = 0; k < HH; ++k) {
            float cv0 = cembL[(lhi * 4 + 0) * HH + k];
            float cv1 = cembL[(lhi * 4 + 1) * HH + k];
            float cv2 = cembL[(lhi * 4 + 2) * HH + k];
            float cv3 = cembL[(lhi * 4 + 3) * HH + k];
            #pragma unroll
            for (int q = 0; q < 4; ++q) {
                float wv = Wih0[(INDIM + k) * GG + colq[q]];
                cz[q][0] = fmaf(cv0, wv, cz[q][0]);
                cz[q][1] = fmaf(cv1, wv, cz[q][1]);
                cz[q][2] = fmaf(cv2, wv, cz[q][2]);
                cz[q][3] = fmaf(cv3, wv, cz[q][3]);
            }
        }
        __syncthreads();   // all cembL reads done before czLh overwrites region
        // plane p = q>>1: czLh[p*4096 + tid*8 + (q&1)*4 + r]
        #pragma unroll
        for (int q = 0; q < 4; ++q)
            #pragma unroll
            for (int r = 0; r < 4; ++r)
                czLh[(q >> 1) * 4096 + tid * 8 + (q & 1) * 4 + r] = (_Float16)cz[q][r];
    }

    // ---- wprev (12 loop-invariant regs) ----
    float wprev[4][3];
    #pragma unroll
    for (int q = 0; q < 4; ++q)
        #pragma unroll
        for (int d = 0; d < 3; ++d) wprev[q][d] = Wih0[d * GG + (w + 8 * q) * 16 + lo16];
    const float bov  = (pl < OD) ? bo[pl] : 0.f;
    const int   plen = lengths[b_base + om];

    // ---- resident weight fragments -> AGPRs (exactly 32 frags = 128 AGPR) ----
    const uint4* __restrict__ w0g = reinterpret_cast<const uint4*>(wf) + (w * 256 + l);
    const uint4* __restrict__ w1g = reinterpret_cast<const uint4*>(wf + W1F_OFF) + (w * 512 + l);
    uint4 w0r[16];   // L0: f = ks*4+q, ks 0..3
    uint4 w1r[16];   // L1: f = ks*4+q, ks 0..3 only
    #pragma unroll
    for (int f = 0; f < 16; ++f) {
        w0r[f] = w0g[(f & 3) * 2048 + (f >> 2) * 64];
        pinA(w0r[f]);
    }
    #pragma unroll
    for (int f = 0; f < 16; ++f) {
        w1r[f] = w1g[(f & 3) * 4096 + (f >> 2) * 64];
        pinA(w1r[f]);
    }
    __syncthreads();

    float c0s[4] = {0.f, 0.f, 0.f, 0.f};
    float c1s[4] = {0.f, 0.f, 0.f, 0.f};

    for (int t = 0; t < TT; ++t) {
        _Float16* Ac = (t & 1) ? A1 : A0;
        _Float16* An = (t & 1) ? A0 : A1;
        const f16x8* apC = reinterpret_cast<const f16x8*>(Ac + lo16 * LDA);
        const f16x8* apN = reinterpret_cast<const f16x8*>(An + lo16 * LDA);

        // opaque zero: makes streamed-load addresses loop-variant to the
        // compiler (blocks LICM hoist -> re-spill of loop-invariant loads)
        unsigned zofs = 0;
        asm volatile("" : "+v"(zofs));
        const uint4* w1s = reinterpret_cast<const uint4*>(
            reinterpret_cast<const unsigned char*>(w1g) + zofs);

        // ---- stream batch A: L1 ks4,5 (consumed mid-P2; ~full-step lead) ----
        uint4 sA[8];
        #pragma unroll
        for (int fi = 0; fi < 8; ++fi) {
            const int ks = 4 + (fi >> 2), q = fi & 3;
            sA[fi] = w1s[q * 4096 + ks * 64];
        }

        // prefetch per-step inputs
        const float tfv = tf_rand[t * BB + b_base + om];
        float tgtv = 0.f;
        if (pl < OD) tgtv = target_seq[((b_base + om) * TT + t) * OD + pl];

        f32x4 acc[4];

        // ---- P0: z0 = cz(LDS) + prev@Wp + h0old@Whh0 ----
        {
            const f16x8 cz01 = *reinterpret_cast<const f16x8*>(czLh + tid * 8);
            const f16x8 cz23 = *reinterpret_cast<const f16x8*>(czLh + 4096 + tid * 8);
            acc[0] = {(float)cz01[0], (float)cz01[1], (float)cz01[2], (float)cz01[3]};
            acc[1] = {(float)cz01[4], (float)cz01[5], (float)cz01[6], (float)cz01[7]};
            acc[2] = {(float)cz23[0], (float)cz23[1], (float)cz23[2], (float)cz23[3]};
            acc[3] = {(float)cz23[4], (float)cz23[5], (float)cz23[6], (float)cz23[7]};
        }
        #pragma unroll
        for (int r = 0; r < 4; ++r) {
            const float4 pv = *reinterpret_cast<const float4*>(prevs + (lhi * 4 + r) * 4);
            #pragma unroll
            for (int q = 0; q < 4; ++q)
                acc[q][r] = fmaf(pv.z, wprev[q][2],
                            fmaf(pv.y, wprev[q][1],
                            fmaf(pv.x, wprev[q][0], acc[q][r])));
        }
        #pragma unroll
        for (int ks = 0; ks < 4; ++ks) {
            const f16x8 a = apC[ks * 4 + lhi];
            #pragma unroll
            for (int q = 0; q < 4; ++q)
                acc[q] = __builtin_amdgcn_mfma_f32_16x16x32_f16(
                             a, __builtin_bit_cast(f16x8, w0r[ks * 4 + q]), acc[q], 0, 0, 0);
        }

        // ---- P1: gate-0 (lane-local), write h0new -> An ----
        #pragma unroll
        for (int r = 0; r < 4; ++r) {
            const float zi = acc[0][r], zf = acc[1][r], zg = acc[2][r], zo = acc[3][r];
            c0s[r] = sigf(zf) * c0s[r] + sigf(zi) * tanhfast(zg);
            An[(lhi * 4 + r) * LDA + w * 16 + lo16] = (_Float16)(sigf(zo) * tanhfast(c0s[r]));
        }

        // ---- stream batch B: L1 ks6,7 (consumed end of P2; barrier lead) ----
        uint4 sB[8];
        #pragma unroll
        for (int fi = 0; fi < 8; ++fi) {
            const int ks = 6 + (fi >> 2), q = fi & 3;
            sB[fi] = w1s[q * 4096 + ks * 64];
        }
        __syncthreads();   // bar_a: h0new visible

        // ---- P2: z1 = b1 + [h0new ; h1old] @ W1 ----
        #pragma unroll
        for (int q = 0; q < 4; ++q) {
            const float bv = b1t[(w * 4 + q) * 16 + lo16];
            acc[q] = {bv, bv, bv, bv};
        }
        #pragma unroll
        for (int ks = 0; ks < 8; ++ks) {
            const f16x8 a = (ks < 4) ? apN[ks * 4 + lhi]
                                     : apC[16 + (ks - 4) * 4 + lhi];
            #pragma unroll
            for (int q = 0; q < 4; ++q) {
                f16x8 b;
                if (ks < 4)      b = __builtin_bit_cast(f16x8, w1r[ks * 4 + q]);
                else if (ks < 6) b = __builtin_bit_cast(f16x8, sA[(ks - 4) * 4 + q]);
                else             b = __builtin_bit_cast(f16x8, sB[(ks - 6) * 4 + q]);
                acc[q] = __builtin_amdgcn_mfma_f32_16x16x32_f16(a, b, acc[q], 0, 0, 0);
            }
        }

        // ---- P3: gate-1 (lane-local), write h1new -> An ----
        #pragma unroll
        for (int r = 0; r < 4; ++r) {
            const float zi = acc[0][r], zf = acc[1][r], zg = acc[2][r], zo = acc[3][r];
            c1s[r] = sigf(zf) * c1s[r] + sigf(zi) * tanhfast(zg);
            An[(lhi * 4 + r) * LDA + HH + w * 16 + lo16] = (_Float16)(sigf(zo) * tanhfast(c1s[r]));
        }
        __syncthreads();   // bar_b: h1new visible

        // ---- P4: output projection + teacher forcing ----
        {
            const f16x4 hv = *reinterpret_cast<const f16x4*>(An + om * LDA + HH + pl * 4);
            const float h0_ = (float)hv[0], h1_ = (float)hv[1],
                        h2_ = (float)hv[2], h3_ = (float)hv[3];
            const float4 wv0 = *reinterpret_cast<const float4*>(WoT + 0 * 128 + pl * 4);
            const float4 wv1 = *reinterpret_cast<const float4*>(WoT + 1 * 128 + pl * 4);
            const float4 wv2 = *reinterpret_cast<const float4*>(WoT + 2 * 128 + pl * 4);
            float s0 = fmaf(h3_, wv0.w, fmaf(h2_, wv0.z, fmaf(h1_, wv0.y, h0_ * wv0.x)));
            float s1 = fmaf(h3_, wv1.w, fmaf(h2_, wv1.z, fmaf(h1_, wv1.y, h0_ * wv1.x)));
            float s2 = fmaf(h3_, wv2.w, fmaf(h2_, wv2.z, fmaf(h1_, wv2.y, h0_ * wv2.x)));
            #pragma unroll
            for (int sh = 16; sh >= 1; sh >>= 1) {
                s0 += __shfl_xor(s0, sh, 32);
                s1 += __shfl_xor(s1, sh, 32);
                s2 += __shfl_xor(s2, sh, 32);
            }
            if (pl < OD) {
                const float sv = (pl == 0) ? s0 : (pl == 1) ? s1 : s2;
                const float pred = sv + bov;
                const int bg = b_base + om;
                out[(bg * TT + t) * OD + pl] = pred;
                const bool use_tf = (tfv < 0.5f) && (t < plen);
                prevs[om * 4 + pl] = use_tf ? tgtv : pred;
            }
        }
        __syncthreads();   // bar_c: prevs ready for next step
    }
}

extern "C" void kernel_launch(void* const* d_in, const int* in_sizes, int n_in,
                              void* d_out, int out_size, void* d_ws, size_t ws_size,
                              hipStream_t stream) {
    const float* conds   = (const float*)d_in[0];
    const float* target  = (const float*)d_in[1];
    const int*   lengths = (const int*)d_in[2];
    const float* tfr     = (const float*)d_in[3];
    const float* Wc      = (const float*)d_in[4];
    const float* bc      = (const float*)d_in[5];
    const float* Wih0    = (const float*)d_in[6];
    const float* Whh0    = (const float*)d_in[7];
    const float* b0      = (const float*)d_in[8];
    const float* Wih1    = (const float*)d_in[9];
    const float* Whh1    = (const float*)d_in[10];
    const float* b1      = (const float*)d_in[11];
    const float* Wo      = (const float*)d_in[12];
    const float* bo      = (const float*)d_in[13];
    float* out = (float*)d_out;
    _Float16* wf = (_Float16*)d_ws;

    repack_frag_kernel<<<WF_TOTAL / 256, 256, 0, stream>>>(Whh0, Wih1, Whh1, wf);
    dubins_lstm_mfma_kernel<<<BB / EPB, 512, 0, stream>>>(
        conds, target, lengths, tfr, Wc, bc,
        Wih0, b0, b1, Wo, bo, wf, out);
}

// Round 10
// 1305.687 us; speedup vs baseline: 1.0921x; 1.0083x over previous
//
#include <hip/hip_runtime.h>

// DubinsLSTM R10: budget-exact split, minimal diff from R7 (proven correct).
// Evidence R4->R9: dur ~linear in streamed frags (16us/frag) + ~85% idle ->
// in-loop arch-class spill. Arch budget observed = 128 (VGPR_Count); accum=128.
// R10: AGPR 32 frags (=128 exact, R9-proven pinA) + 5 frags in LDS (R7 path)
// + 11 frags streamed once per step at loop top (44 arch regs, ~600cy lead).
// Arch peak audit ~112 < 128. If dur doesn't collapse, spill-hypothesis is
// falsified -> restructure for occupancy next.

#define BB 1024
#define TT 200
#define INDIM 3
#define CDIM 4
#define HH 128
#define OD 3
#define GG 512
#define EPB 16
#define LDA 264              // halves; 528B row stride
#define W1F_OFF 65536        // halves
#define WF_TOTAL 196608      // halves (384 KB)

// smem blob (bytes) — identical to R7:
#define A1_OFF    8448       // A0 [16][264] f16
#define WLDS_OFF  16896      // 5 frags x 8 waves x 64 lanes x 16B = 40960
#define B1T_OFF   57856      // b1t [8][4][16] f32 = 2048
#define WOT_OFF   59904      // WoT [3][128] f32 = 1536
#define PREVS_OFF 61440      // prevs [16][4] f32 = 256
#define SMEM_SZ   61696

typedef _Float16 f16x8 __attribute__((ext_vector_type(8)));
typedef _Float16 f16x4 __attribute__((ext_vector_type(4)));
typedef float f32x4 __attribute__((ext_vector_type(4)));

__device__ __forceinline__ float sigf(float x) {
    return __fdividef(1.f, 1.f + __expf(-x));
}
__device__ __forceinline__ float tanhfast(float x) {
    return 1.f - __fdividef(2.f, __expf(2.f * x) + 1.f);
}
// pin a 16B fragment into AGPRs (unified file; MFMA reads A/B from AGPR)
__device__ __forceinline__ void pinA(uint4& v) {
    asm volatile("" : "+a"(v.x), "+a"(v.y), "+a"(v.z), "+a"(v.w));
}

// Repack Whh0 / [Wih1;Whh1] into MFMA-B fragment-linear f16 (layout verified
// R4+): frag(nt,ks): lane l holds B[k=ks*32+8*(l>>4)+j][col=nt*16+(l&15)].
__global__ void repack_frag_kernel(const float* __restrict__ Whh0,
                                   const float* __restrict__ Wih1,
                                   const float* __restrict__ Whh1,
                                   _Float16* __restrict__ wf) {
    int idx = blockIdx.x * 256 + threadIdx.x;
    if (idx < 65536) {
        int nt = idx >> 11;
        int ks = (idx >> 9) & 3;
        int l  = (idx >> 3) & 63;
        int j  = idx & 7;
        int k  = ks * 32 + ((l >> 4) << 3) + j;
        int col = nt * 16 + (l & 15);
        wf[idx] = (_Float16)Whh0[k * GG + col];
    } else {
        int i2 = idx - 65536;
        int nt = i2 >> 12;
        int ks = (i2 >> 9) & 7;
        int l  = (i2 >> 3) & 63;
        int j  = i2 & 7;
        int k  = ks * 32 + ((l >> 4) << 3) + j;
        int col = nt * 16 + (l & 15);
        float v = (k < HH) ? Wih1[k * GG + col] : Whh1[(k - HH) * GG + col];
        wf[idx] = (_Float16)v;
    }
}

__global__ __attribute__((amdgpu_waves_per_eu(2, 2)))
__launch_bounds__(512) void dubins_lstm_mfma_kernel(
    const float* __restrict__ conds,
    const float* __restrict__ target_seq,
    const int*   __restrict__ lengths,
    const float* __restrict__ tf_rand,
    const float* __restrict__ Wc,
    const float* __restrict__ bc,
    const float* __restrict__ Wih0,
    const float* __restrict__ b0,
    const float* __restrict__ b1,
    const float* __restrict__ Wo,
    const float* __restrict__ bo,
    const _Float16* __restrict__ wf,
    float* __restrict__ out)
{
    __shared__ __align__(16) unsigned char smem[SMEM_SZ];
    _Float16* A0    = (_Float16*)smem;
    _Float16* A1    = (_Float16*)(smem + A1_OFF);
    uint4*    wldsU = (uint4*)(smem + WLDS_OFF);
    float*    cembL = (float*)(smem + WLDS_OFF);    // alias: pre-loop only
    float*    b1t   = (float*)(smem + B1T_OFF);     // [w][q][u]
    float*    WoT   = (float*)(smem + WOT_OFF);     // [d][k]
    float*    prevs = (float*)(smem + PREVS_OFF);   // [m][4]

    const int tid  = threadIdx.x;
    const int w    = tid >> 6;
    const int l    = tid & 63;
    const int lo16 = l & 15;
    const int lhi  = l >> 4;
    const int b_base = blockIdx.x * EPB;
    const int om = tid >> 5;       // P4 element
    const int pl = tid & 31;       // P4 lane

    // ---- zero A0+A1, prevs; fill b1t, WoT ----
    for (int i = tid; i < 4224; i += 512) ((unsigned int*)smem)[i] = 0u;
    if (tid < 64) prevs[tid] = 0.f;
    {   // b1t[w][q][u] = b1[(w+8q)*16+u]
        int fw = tid >> 6, fq = (tid >> 4) & 3, fu = tid & 15;
        b1t[tid] = b1[(fw + 8 * fq) * 16 + fu];
    }
    if (tid < 384) WoT[(tid % 3) * 128 + tid / 3] = Wo[tid];

    // ---- cemb[m][k] (f32, aliased LDS) ----
    {
        int m  = tid >> 5;
        int k0 = (tid & 31) * 4;
        float cd[CDIM];
        #pragma unroll
        for (int d = 0; d < CDIM; ++d) cd[d] = conds[(b_base + m) * CDIM + d];
        #pragma unroll
        for (int kk = 0; kk < 4; ++kk) {
            int k = k0 + kk;
            float v = bc[k];
            #pragma unroll
            for (int d = 0; d < CDIM; ++d) v = fmaf(cd[d], Wc[d * HH + k], v);
            cembL[m * HH + k] = v;
        }
    }
    __syncthreads();

    // ---- cz (time-invariant C-init) -> per-thread packed f16 regs ----
    f16x4 czp[4];
    {
        f32x4 cz[4];
        int colq[4];
        #pragma unroll
        for (int q = 0; q < 4; ++q) {
            colq[q] = (w + 8 * q) * 16 + lo16;
            float bz = b0[colq[q]];
            cz[q] = {bz, bz, bz, bz};
        }
        for (int k = 0; k < HH; ++k) {
            float cv0 = cembL[(lhi * 4 + 0) * HH + k];
            float cv1 = cembL[(lhi * 4 + 1) * HH + k];
            float cv2 = cembL[(lhi * 4 + 2) * HH + k];
            float cv3 = cembL[(lhi * 4 + 3) * HH + k];
            #pragma unroll
            for (int q = 0; q < 4; ++q) {
                float wv = Wih0[(INDIM + k) * GG + colq[q]];
                cz[q][0] = fmaf(cv0, wv, cz[q][0]);
                cz[q][1] = fmaf(cv1, wv, cz[q][1]);
                cz[q][2] = fmaf(cv2, wv, cz[q][2]);
                cz[q][3] = fmaf(cv3, wv, cz[q][3]);
            }
        }
        #pragma unroll
        for (int q = 0; q < 4; ++q)
            #pragma unroll
            for (int r = 0; r < 4; ++r) czp[q][r] = (_Float16)cz[q][r];
        __syncthreads();   // cembL reads done; wlds region may be overwritten
    }

    // ---- wprev (12 loop-invariant regs) ----
    float wprev[4][3];
    #pragma unroll
    for (int q = 0; q < 4; ++q)
        #pragma unroll
        for (int d = 0; d < 3; ++d) wprev[q][d] = Wih0[d * GG + (w + 8 * q) * 16 + lo16];
    const float bov  = (pl < OD) ? bo[pl] : 0.f;
    const int   plen = lengths[b_base + om];

    // ---- resident frags: 32 -> AGPR (=128 exact); 5 -> LDS; 11 streamed ----
    const uint4* __restrict__ w0g = reinterpret_cast<const uint4*>(wf) + (w * 256 + l);
    const uint4* __restrict__ w1g = reinterpret_cast<const uint4*>(wf + W1F_OFF) + (w * 512 + l);
    uint4 w0r[16];   // L0: f = ks*4+q, ks 0..3
    uint4 w1r[16];   // L1: f = ks*4+q, ks 0..3
    #pragma unroll
    for (int f = 0; f < 16; ++f) {
        w0r[f] = w0g[(f & 3) * 2048 + (f >> 2) * 64];
        pinA(w0r[f]);
    }
    #pragma unroll
    for (int f = 0; f < 16; ++f) {
        w1r[f] = w1g[(f & 3) * 4096 + (f >> 2) * 64];
        pinA(w1r[f]);
    }
    #pragma unroll
    for (int fi = 0; fi < 5; ++fi) {
        int f = 27 + fi, ks = f >> 2, q = f & 3;
        wldsU[(w * 5 + fi) * 64 + l] = w1g[q * 4096 + ks * 64];
    }
    __syncthreads();

    float c0s[4] = {0.f, 0.f, 0.f, 0.f};
    float c1s[4] = {0.f, 0.f, 0.f, 0.f};

    for (int t = 0; t < TT; ++t) {
        _Float16* Ac = (t & 1) ? A1 : A0;
        _Float16* An = (t & 1) ? A0 : A1;
        const f16x8* apC = reinterpret_cast<const f16x8*>(Ac + lo16 * LDA);
        const f16x8* apN = reinterpret_cast<const f16x8*>(An + lo16 * LDA);

        // opaque zero: blocks LICM hoist (-> re-spill) of the streamed loads
        unsigned zofs = 0;
        asm volatile("" : "+v"(zofs));
        const uint4* w1s = reinterpret_cast<const uint4*>(
            reinterpret_cast<const unsigned char*>(w1g) + zofs);

        // ---- stream 11 frags (f=16..26), one batch, consumed mid-P2 ----
        uint4 sS[11];
        #pragma unroll
        for (int fi = 0; fi < 11; ++fi) {
            const int f = 16 + fi, ks = f >> 2, q = f & 3;
            sS[fi] = w1s[q * 4096 + ks * 64];
        }

        f32x4 acc[4];

        // ---- P0: z0 = cz + prev@Wp + h0old@Whh0 ----
        #pragma unroll
        for (int q = 0; q < 4; ++q)
            acc[q] = {(float)czp[q][0], (float)czp[q][1],
                      (float)czp[q][2], (float)czp[q][3]};
        #pragma unroll
        for (int r = 0; r < 4; ++r) {
            const float4 pv = *reinterpret_cast<const float4*>(prevs + (lhi * 4 + r) * 4);
            #pragma unroll
            for (int q = 0; q < 4; ++q)
                acc[q][r] = fmaf(pv.z, wprev[q][2],
                            fmaf(pv.y, wprev[q][1],
                            fmaf(pv.x, wprev[q][0], acc[q][r])));
        }
        #pragma unroll
        for (int ks = 0; ks < 4; ++ks) {
            const f16x8 a = apC[ks * 4 + lhi];
            #pragma unroll
            for (int q = 0; q < 4; ++q)
                acc[q] = __builtin_amdgcn_mfma_f32_16x16x32_f16(
                             a, __builtin_bit_cast(f16x8, w0r[ks * 4 + q]), acc[q], 0, 0, 0);
        }

        // ---- P1: gate-0 (lane-local), write h0new -> An ----
        #pragma unroll
        for (int r = 0; r < 4; ++r) {
            const float zi = acc[0][r], zf = acc[1][r], zg = acc[2][r], zo = acc[3][r];
            c0s[r] = sigf(zf) * c0s[r] + sigf(zi) * tanhfast(zg);
            An[(lhi * 4 + r) * LDA + w * 16 + lo16] = (_Float16)(sigf(zo) * tanhfast(c0s[r]));
        }
        __syncthreads();   // bar_a: h0new visible (streamed loads long complete)

        // per-step inputs (consumed in P4; issued here, drained at bar_b)
        const float tfv = tf_rand[t * BB + b_base + om];
        float tgtv = 0.f;
        if (pl < OD) tgtv = target_seq[((b_base + om) * TT + t) * OD + pl];

        // ---- P2: z1 = b1 + [h0new ; h1old] @ W1 ----
        #pragma unroll
        for (int q = 0; q < 4; ++q) {
            const float bv = b1t[(w * 4 + q) * 16 + lo16];
            acc[q] = {bv, bv, bv, bv};
        }
        #pragma unroll
        for (int ks = 0; ks < 8; ++ks) {
            const f16x8 a = (ks < 4) ? apN[ks * 4 + lhi]
                                     : apC[16 + (ks - 4) * 4 + lhi];
            #pragma unroll
            for (int q = 0; q < 4; ++q) {
                const int f = ks * 4 + q;
                f16x8 b;
                if (f < 16)      b = __builtin_bit_cast(f16x8, w1r[f]);
                else if (f < 27) b = __builtin_bit_cast(f16x8, sS[f - 16]);
                else             b = __builtin_bit_cast(f16x8, wldsU[(w * 5 + (f - 27)) * 64 + l]);
                acc[q] = __builtin_amdgcn_mfma_f32_16x16x32_f16(a, b, acc[q], 0, 0, 0);
            }
        }

        // ---- P3: gate-1 (lane-local), write h1new -> An ----
        #pragma unroll
        for (int r = 0; r < 4; ++r) {
            const float zi = acc[0][r], zf = acc[1][r], zg = acc[2][r], zo = acc[3][r];
            c1s[r] = sigf(zf) * c1s[r] + sigf(zi) * tanhfast(zg);
            An[(lhi * 4 + r) * LDA + HH + w * 16 + lo16] = (_Float16)(sigf(zo) * tanhfast(c1s[r]));
        }
        __syncthreads();   // bar_b: h1new visible

        // ---- P4: output projection + teacher forcing ----
        {
            const f16x4 hv = *reinterpret_cast<const f16x4*>(An + om * LDA + HH + pl * 4);
            const float h0_ = (float)hv[0], h1_ = (float)hv[1],
                        h2_ = (float)hv[2], h3_ = (float)hv[3];
            const float4 wv0 = *reinterpret_cast<const float4*>(WoT + 0 * 128 + pl * 4);
            const float4 wv1 = *reinterpret_cast<const float4*>(WoT + 1 * 128 + pl * 4);
            const float4 wv2 = *reinterpret_cast<const float4*>(WoT + 2 * 128 + pl * 4);
            float s0 = fmaf(h3_, wv0.w, fmaf(h2_, wv0.z, fmaf(h1_, wv0.y, h0_ * wv0.x)));
            float s1 = fmaf(h3_, wv1.w, fmaf(h2_, wv1.z, fmaf(h1_, wv1.y, h0_ * wv1.x)));
            float s2 = fmaf(h3_, wv2.w, fmaf(h2_, wv2.z, fmaf(h1_, wv2.y, h0_ * wv2.x)));
            #pragma unroll
            for (int sh = 16; sh >= 1; sh >>= 1) {
                s0 += __shfl_xor(s0, sh, 32);
                s1 += __shfl_xor(s1, sh, 32);
                s2 += __shfl_xor(s2, sh, 32);
            }
            if (pl < OD) {
                const float sv = (pl == 0) ? s0 : (pl == 1) ? s1 : s2;
                const float pred = sv + bov;
                const int bg = b_base + om;
                out[(bg * TT + t) * OD + pl] = pred;
                const bool use_tf = (tfv < 0.5f) && (t < plen);
                prevs[om * 4 + pl] = use_tf ? tgtv : pred;
            }
        }
        __syncthreads();   // bar_c: prevs ready for next step
    }
}

extern "C" void kernel_launch(void* const* d_in, const int* in_sizes, int n_in,
                              void* d_out, int out_size, void* d_ws, size_t ws_size,
                              hipStream_t stream) {
    const float* conds   = (const float*)d_in[0];
    const float* target  = (const float*)d_in[1];
    const int*   lengths = (const int*)d_in[2];
    const float* tfr     = (const float*)d_in[3];
    const float* Wc      = (const float*)d_in[4];
    const float* bc      = (const float*)d_in[5];
    const float* Wih0    = (const float*)d_in[6];
    const float* Whh0    = (const float*)d_in[7];
    const float* b0      = (const float*)d_in[8];
    const float* Wih1    = (const float*)d_in[9];
    const float* Whh1    = (const float*)d_in[10];
    const float* b1      = (const float*)d_in[11];
    const float* Wo      = (const float*)d_in[12];
    const float* bo      = (const float*)d_in[13];
    float* out = (float*)d_out;
    _Float16* wf = (_Float16*)d_ws;

    repack_frag_kernel<<<WF_TOTAL / 256, 256, 0, stream>>>(Whh0, Wih1, Whh1, wf);
    dubins_lstm_mfma_kernel<<<BB / EPB, 512, 0, stream>>>(
        conds, target, lengths, tfr, Wc, bc,
        Wih0, b0, b1, Wo, bo, wf, out);
}